// Round 2
// baseline (139.201 us; speedup 1.0000x reference)
//
#include <hip/hip_runtime.h>
#include <hip/hip_bf16.h>

#define M_DIM 4096
#define N_DIM 16384
#define K_DIM 256

typedef short short8 __attribute__((ext_vector_type(8)));
typedef float f32x4 __attribute__((ext_vector_type(4)));
typedef unsigned int u32x4 __attribute__((ext_vector_type(4)));

// fp32 -> bf16 (RNE) pack of two floats into one u32 (lo = first elem)
__device__ __forceinline__ unsigned int pk2bf(float lo, float hi) {
    unsigned int a = __float_as_uint(lo);
    unsigned int b = __float_as_uint(hi);
    a = (a + 0x7FFFu + ((a >> 16) & 1u)) >> 16;
    b = (b + 0x7FFFu + ((b >> 16) & 1u)) & 0xFFFF0000u;
    return a | b;
}

// ---------------------------------------------------------------------------
// Merged pre-pass (one launch):
//   blocks [0,256):  W [K][N] f32 -> Wt [N][K] bf16 with mask baked in:
//                    Wt[n][k] = (k == n/64) ? 0 : W[k][n]
//   blocks [256,768): x [M][K] f32 -> xb bf16 flat
// ---------------------------------------------------------------------------
__global__ __launch_bounds__(256) void convert_kernel(const float* __restrict__ W,
                                                      const float* __restrict__ x,
                                                      unsigned short* __restrict__ Wt,
                                                      unsigned short* __restrict__ xb) {
    const int bx = blockIdx.x;
    if (bx < 256) {
        const int n  = (bx & 63) * 256 + threadIdx.x;
        const int k0 = (bx >> 6) * 64;
        const int jm = n >> 6;  // masked k for this output row
        #pragma unroll
        for (int kk = 0; kk < 64; kk += 8) {
            float v[8];
            #pragma unroll
            for (int j = 0; j < 8; ++j) {
                const int k = k0 + kk + j;
                float f = W[(size_t)k * N_DIM + n];
                v[j] = (k == jm) ? 0.0f : f;
            }
            u32x4 p = { pk2bf(v[0], v[1]), pk2bf(v[2], v[3]),
                        pk2bf(v[4], v[5]), pk2bf(v[6], v[7]) };
            *(u32x4*)(Wt + (size_t)n * K_DIM + k0 + kk) = p;
        }
    } else {
        const size_t base = ((size_t)(bx - 256) * 256 + threadIdx.x) * 8;
        float4 a = *(const float4*)(x + base);
        float4 b = *(const float4*)(x + base + 4);
        u32x4 p = { pk2bf(a.x, a.y), pk2bf(a.z, a.w),
                    pk2bf(b.x, b.y), pk2bf(b.z, b.w) };
        *(u32x4*)(xb + base) = p;
    }
}

// ---------------------------------------------------------------------------
// Main GEMM: out[M][N] = Abf[M][K] (bf16) @ Wt[N][K]^T (bf16) + bias, fp32 out.
// 128x128 tile, BK=64, 4 waves (2x2), each wave 64x64 via 4x4 frags of
// mfma_f32_16x16x32_bf16. Operands SWAPPED (mfma(b,a)) so D[n][m] layout puts
// 4 consecutive N per lane -> f32x4 nontemporal stores (write-BW bound kernel).
// ---------------------------------------------------------------------------
constexpr int BM = 128, BN = 128, BK = 64;

__global__ __launch_bounds__(256, 2) void gemm_kernel(
        const unsigned short* __restrict__ Abf,   // [M][K] bf16
        const unsigned short* __restrict__ Bbf,   // [N][K] bf16 (W transposed, masked)
        const float* __restrict__ bias,           // [N] f32
        float* __restrict__ out) {                // [M][N] f32
    __shared__ unsigned short As[2][BM][BK];
    __shared__ unsigned short Bs[2][BN][BK];

    // XCD-aware swizzle (4096 blocks, 8 XCDs -> 512 contiguous per XCD),
    // m-fast so 32 consecutive blocks share one B panel.
    const int bid = blockIdx.x;
    const int sw  = (bid & 7) * 512 + (bid >> 3);
    const int m0  = (sw & 31) * BM;
    const int n0  = (sw >> 5) * BN;

    const int t    = threadIdx.x;
    const int lane = t & 63;
    const int wave = t >> 6;
    const int wm   = (wave >> 1) * 64;   // wave row offset in tile
    const int wn   = (wave & 1) * 64;    // wave col offset in tile
    const int lr   = lane & 15;          // fragment row/col index
    const int lk   = (lane >> 4) * 8;    // fragment k offset (elems)

    // staging geometry: thread covers row srow(+32r), 8 elems at selk
    const int srow = t >> 3;             // 0..31
    const int selk = (t & 7) * 8;        // 0..56

    const unsigned short* gA = Abf + (size_t)(m0 + srow) * K_DIM + selk;
    const unsigned short* gB = Bbf + (size_t)(n0 + srow) * K_DIM + selk;

    u32x4 ra[4], rb[4];

    auto ldreg = [&](int kt) {
        #pragma unroll
        for (int r = 0; r < 4; ++r) {
            ra[r] = *(const u32x4*)(gA + (size_t)(r * 32) * K_DIM + kt * BK);
            rb[r] = *(const u32x4*)(gB + (size_t)(r * 32) * K_DIM + kt * BK);
        }
    };
    auto dswrite = [&](int buf) {
        #pragma unroll
        for (int r = 0; r < 4; ++r) {
            const int row = srow + r * 32;
            const int c   = selk ^ ((row & 7) << 3);   // bank swizzle (elems)
            *(u32x4*)&As[buf][row][c] = ra[r];
            *(u32x4*)&Bs[buf][row][c] = rb[r];
        }
    };

    f32x4 acc[4][4] = {};

    ldreg(0);
    dswrite(0);
    __syncthreads();

    #pragma unroll
    for (int kt = 0; kt < 4; ++kt) {
        const int buf = kt & 1;
        if (kt < 3) ldreg(kt + 1);    // issue next-tile loads; latency hides under MFMA
        #pragma unroll
        for (int ks = 0; ks < 2; ++ks) {
            short8 af[4], bfr[4];
            #pragma unroll
            for (int mi = 0; mi < 4; ++mi) {
                const int row = wm + mi * 16 + lr;
                const int c   = (ks * 32 + lk) ^ ((row & 7) << 3);
                af[mi] = *(const short8*)&As[buf][row][c];
            }
            #pragma unroll
            for (int ni = 0; ni < 4; ++ni) {
                const int row = wn + ni * 16 + lr;
                const int c   = (ks * 32 + lk) ^ ((row & 7) << 3);
                bfr[ni] = *(const short8*)&Bs[buf][row][c];
            }
            // Swapped operands: D[n][m]; C-layout col(lane&15)=m, row=(lane>>4)*4+j=n
            #pragma unroll
            for (int mi = 0; mi < 4; ++mi)
                #pragma unroll
                for (int ni = 0; ni < 4; ++ni)
                    acc[mi][ni] = __builtin_amdgcn_mfma_f32_16x16x32_bf16(
                        bfr[ni], af[mi], acc[mi][ni], 0, 0, 0);
        }
        if (kt < 3) {
            dswrite(buf ^ 1);
            __syncthreads();
        }
    }

    // epilogue: each lane holds 4 CONSECUTIVE n per fragment -> f32x4 NT stores
    const int om      = m0 + wm + (lane & 15);
    const int on_base = n0 + wn + (lane >> 4) * 4;
    #pragma unroll
    for (int ni = 0; ni < 4; ++ni) {
        const int n = on_base + ni * 16;
        const float4 bv = *(const float4*)(bias + n);
        #pragma unroll
        for (int mi = 0; mi < 4; ++mi) {
            f32x4 v = acc[mi][ni];
            v[0] += bv.x; v[1] += bv.y; v[2] += bv.z; v[3] += bv.w;
            f32x4* p = (f32x4*)(out + (size_t)(om + mi * 16) * N_DIM + n);
            __builtin_nontemporal_store(v, p);
        }
    }
}

// ---------------------------------------------------------------------------
// Fallback (only if d_ws is too small): direct fp32, slow but correct.
// ---------------------------------------------------------------------------
__global__ __launch_bounds__(256) void fallback_kernel(const float* __restrict__ x,
                                                       const float* __restrict__ W,
                                                       const float* __restrict__ bias,
                                                       float* __restrict__ out) {
    const size_t gid = (size_t)blockIdx.x * 256 + threadIdx.x;
    const size_t row = gid / (N_DIM / 8);
    const int    c0  = (int)(gid % (N_DIM / 8)) * 8;
    const int    jm  = c0 >> 6;   // whole 8-wide chunk lies in one 64-block
    float acc[8] = {0, 0, 0, 0, 0, 0, 0, 0};
    const float* xr = x + row * K_DIM;
    for (int k = 0; k < K_DIM; ++k) {
        const float xv = (k == jm) ? 0.0f : xr[k];
        const float4* wr = (const float4*)(W + (size_t)k * N_DIM + c0);
        float4 w0 = wr[0], w1 = wr[1];
        acc[0] += xv * w0.x; acc[1] += xv * w0.y;
        acc[2] += xv * w0.z; acc[3] += xv * w0.w;
        acc[4] += xv * w1.x; acc[5] += xv * w1.y;
        acc[6] += xv * w1.z; acc[7] += xv * w1.w;
    }
    float* o = out + row * N_DIM + c0;
    #pragma unroll
    for (int j = 0; j < 8; ++j) o[j] = acc[j] + bias[c0 + j];
}

// ---------------------------------------------------------------------------
extern "C" void kernel_launch(void* const* d_in, const int* in_sizes, int n_in,
                              void* d_out, int out_size, void* d_ws, size_t ws_size,
                              hipStream_t stream) {
    const float* x    = (const float*)d_in[0];   // [4096, 256]
    const float* W    = (const float*)d_in[1];   // [256, 16384]
    const float* bias = (const float*)d_in[2];   // [16384]
    float* out        = (float*)d_out;           // [4096, 16384]

    const size_t wt_bytes = (size_t)N_DIM * K_DIM * 2;   // 8 MB
    const size_t xb_bytes = (size_t)M_DIM * K_DIM * 2;   // 2 MB

    if (ws_size >= wt_bytes + xb_bytes) {
        unsigned short* Wt = (unsigned short*)d_ws;
        unsigned short* xb = (unsigned short*)((char*)d_ws + wt_bytes);

        convert_kernel<<<256 + (M_DIM * K_DIM / 8) / 256, 256, 0, stream>>>(W, x, Wt, xb);
        gemm_kernel<<<(M_DIM / BM) * (N_DIM / BN), 256, 0, stream>>>(xb, Wt, bias, out);
    } else {
        const size_t total = (size_t)M_DIM * N_DIM / 8;
        fallback_kernel<<<(unsigned)(total / 256), 256, 0, stream>>>(x, W, bias, out);
    }
}

// Round 3
// 88.192 us; speedup vs baseline: 1.5784x; 1.5784x over previous
//
#include <hip/hip_runtime.h>
#include <hip/hip_bf16.h>

#define M_DIM 4096
#define N_DIM 16384
#define K_DIM 256

typedef short short8 __attribute__((ext_vector_type(8)));
typedef float f32x4 __attribute__((ext_vector_type(4)));
typedef unsigned int u32x4 __attribute__((ext_vector_type(4)));

// fp32 -> bf16 (RNE) pack of two floats into one u32 (lo = first elem)
__device__ __forceinline__ unsigned int pk2bf(float lo, float hi) {
    unsigned int a = __float_as_uint(lo);
    unsigned int b = __float_as_uint(hi);
    a = (a + 0x7FFFu + ((a >> 16) & 1u)) >> 16;
    b = (b + 0x7FFFu + ((b >> 16) & 1u)) & 0xFFFF0000u;
    return a | b;
}

// ---------------------------------------------------------------------------
// Merged pre-pass (one launch):
//   blocks [0,256):  W [K][N] f32 -> Wt [N][K] bf16 with mask baked in:
//                    Wt[n][k] = (k == n/64) ? 0 : W[k][n]
//   blocks [256,768): x [M][K] f32 -> xb bf16 flat
// ---------------------------------------------------------------------------
__global__ __launch_bounds__(256) void convert_kernel(const float* __restrict__ W,
                                                      const float* __restrict__ x,
                                                      unsigned short* __restrict__ Wt,
                                                      unsigned short* __restrict__ xb) {
    const int bx = blockIdx.x;
    if (bx < 256) {
        const int n  = (bx & 63) * 256 + threadIdx.x;
        const int k0 = (bx >> 6) * 64;
        const int jm = n >> 6;  // masked k for this output row
        #pragma unroll
        for (int kk = 0; kk < 64; kk += 8) {
            float v[8];
            #pragma unroll
            for (int j = 0; j < 8; ++j) {
                const int k = k0 + kk + j;
                float f = W[(size_t)k * N_DIM + n];
                v[j] = (k == jm) ? 0.0f : f;
            }
            u32x4 p = { pk2bf(v[0], v[1]), pk2bf(v[2], v[3]),
                        pk2bf(v[4], v[5]), pk2bf(v[6], v[7]) };
            *(u32x4*)(Wt + (size_t)n * K_DIM + k0 + kk) = p;
        }
    } else {
        const size_t base = ((size_t)(bx - 256) * 256 + threadIdx.x) * 8;
        float4 a = *(const float4*)(x + base);
        float4 b = *(const float4*)(x + base + 4);
        u32x4 p = { pk2bf(a.x, a.y), pk2bf(a.z, a.w),
                    pk2bf(b.x, b.y), pk2bf(b.z, b.w) };
        *(u32x4*)(xb + base) = p;
    }
}

// ---------------------------------------------------------------------------
// Main GEMM: out[M][N] = Abf[M][K] (bf16) @ Wt[N][K]^T (bf16) + bias, fp32 out.
// 128x128 tile, BK=64, 4 waves (2x2), 4x4 frags of mfma_f32_16x16x32_bf16,
// operands swapped (D[n][m]: lane holds 4 consecutive n). Epilogue stages the
// 64KB fp32 C-tile in LDS (aliasing the As/Bs region after a barrier), then
// reads back row-major so every wave store instruction writes 2 rows x 512 B
// CONTIGUOUS (write-BW-bound kernel; round-2's 64B NT fragments were 2 TB/s).
// ---------------------------------------------------------------------------
constexpr int BM = 128, BN = 128, BK = 64;

__global__ __launch_bounds__(256, 2) void gemm_kernel(
        const unsigned short* __restrict__ Abf,   // [M][K] bf16
        const unsigned short* __restrict__ Bbf,   // [N][K] bf16 (W transposed, masked)
        const float* __restrict__ bias,           // [N] f32
        float* __restrict__ out) {                // [M][N] f32
    // 64 KB shared: As[2][128][64] (32KB) + Bs[2][128][64] (32KB),
    // aliased as float Cs[128][128] (64KB) for the epilogue.
    __shared__ __align__(16) unsigned char smem[65536];
    auto As = (unsigned short (*)[BM][BK])(smem);
    auto Bs = (unsigned short (*)[BN][BK])(smem + 32768);
    float* Cs = (float*)smem;

    // XCD-aware swizzle (4096 blocks, 8 XCDs -> 512 contiguous per XCD),
    // m-fast so 32 consecutive blocks share one B panel.
    const int bid = blockIdx.x;
    const int sw  = (bid & 7) * 512 + (bid >> 3);
    const int m0  = (sw & 31) * BM;
    const int n0  = (sw >> 5) * BN;

    const int t    = threadIdx.x;
    const int lane = t & 63;
    const int wave = t >> 6;
    const int wm   = (wave >> 1) * 64;   // wave row offset in tile
    const int wn   = (wave & 1) * 64;    // wave col offset in tile
    const int lr   = lane & 15;          // fragment row/col index
    const int lk   = (lane >> 4) * 8;    // fragment k offset (elems)

    // staging geometry: thread covers row srow(+32r), 8 elems at selk
    const int srow = t >> 3;             // 0..31
    const int selk = (t & 7) * 8;        // 0..56

    const unsigned short* gA = Abf + (size_t)(m0 + srow) * K_DIM + selk;
    const unsigned short* gB = Bbf + (size_t)(n0 + srow) * K_DIM + selk;

    u32x4 ra[4], rb[4];

    auto ldreg = [&](int kt) {
        #pragma unroll
        for (int r = 0; r < 4; ++r) {
            ra[r] = *(const u32x4*)(gA + (size_t)(r * 32) * K_DIM + kt * BK);
            rb[r] = *(const u32x4*)(gB + (size_t)(r * 32) * K_DIM + kt * BK);
        }
    };
    auto dswrite = [&](int buf) {
        #pragma unroll
        for (int r = 0; r < 4; ++r) {
            const int row = srow + r * 32;
            const int c   = selk ^ ((row & 7) << 3);   // bank swizzle (elems)
            *(u32x4*)&As[buf][row][c] = ra[r];
            *(u32x4*)&Bs[buf][row][c] = rb[r];
        }
    };

    f32x4 acc[4][4] = {};

    ldreg(0);
    dswrite(0);
    __syncthreads();

    #pragma unroll
    for (int kt = 0; kt < 4; ++kt) {
        const int buf = kt & 1;
        if (kt < 3) ldreg(kt + 1);    // issue next-tile loads; latency hides under MFMA
        #pragma unroll
        for (int ks = 0; ks < 2; ++ks) {
            short8 af[4], bfr[4];
            #pragma unroll
            for (int mi = 0; mi < 4; ++mi) {
                const int row = wm + mi * 16 + lr;
                const int c   = (ks * 32 + lk) ^ ((row & 7) << 3);
                af[mi] = *(const short8*)&As[buf][row][c];
            }
            #pragma unroll
            for (int ni = 0; ni < 4; ++ni) {
                const int row = wn + ni * 16 + lr;
                const int c   = (ks * 32 + lk) ^ ((row & 7) << 3);
                bfr[ni] = *(const short8*)&Bs[buf][row][c];
            }
            // Swapped operands: D[n][m]; verified round 2 (absmax 0.5):
            // m = lane&15 (+mi*16), n = (lane>>4)*4 + j (+ni*16)
            #pragma unroll
            for (int mi = 0; mi < 4; ++mi)
                #pragma unroll
                for (int ni = 0; ni < 4; ++ni)
                    acc[mi][ni] = __builtin_amdgcn_mfma_f32_16x16x32_bf16(
                        bfr[ni], af[mi], acc[mi][ni], 0, 0, 0);
        }
        if (kt < 3) {
            dswrite(buf ^ 1);
            __syncthreads();
        }
    }

    // ---- epilogue: acc -> LDS (swizzled) -> coalesced global stores ----
    __syncthreads();   // all waves done reading As/Bs before aliasing as Cs

    {
        const int rl0 = wm + lr;                  // local row for this lane
        const int nl0 = wn + (lane >> 4) * 4;     // local col (float index)
        #pragma unroll
        for (int mi = 0; mi < 4; ++mi) {
            const int rl = rl0 + mi * 16;
            const int sx = (rl & 7) << 2;         // XOR swizzle, 4-float granule
            #pragma unroll
            for (int ni = 0; ni < 4; ++ni) {
                const int nl = (nl0 + ni * 16) ^ sx;
                *(f32x4*)&Cs[rl * BN + nl] = acc[mi][ni];
            }
        }
    }
    __syncthreads();

    {
        const int col4 = (t & 31) * 4;            // float col, 0..124
        const float4 bv = *(const float4*)(bias + n0 + col4);
        #pragma unroll
        for (int p = 0; p < 16; ++p) {
            const int row = p * 8 + (t >> 5);
            const int cs  = col4 ^ ((row & 7) << 2);
            f32x4 v = *(const f32x4*)&Cs[row * BN + cs];
            v[0] += bv.x; v[1] += bv.y; v[2] += bv.z; v[3] += bv.w;
            *(f32x4*)(out + (size_t)(m0 + row) * N_DIM + n0 + col4) = v;
        }
    }
}

// ---------------------------------------------------------------------------
// Fallback (only if d_ws is too small): direct fp32, slow but correct.
// ---------------------------------------------------------------------------
__global__ __launch_bounds__(256) void fallback_kernel(const float* __restrict__ x,
                                                       const float* __restrict__ W,
                                                       const float* __restrict__ bias,
                                                       float* __restrict__ out) {
    const size_t gid = (size_t)blockIdx.x * 256 + threadIdx.x;
    const size_t row = gid / (N_DIM / 8);
    const int    c0  = (int)(gid % (N_DIM / 8)) * 8;
    const int    jm  = c0 >> 6;   // whole 8-wide chunk lies in one 64-block
    float acc[8] = {0, 0, 0, 0, 0, 0, 0, 0};
    const float* xr = x + row * K_DIM;
    for (int k = 0; k < K_DIM; ++k) {
        const float xv = (k == jm) ? 0.0f : xr[k];
        const float4* wr = (const float4*)(W + (size_t)k * N_DIM + c0);
        float4 w0 = wr[0], w1 = wr[1];
        acc[0] += xv * w0.x; acc[1] += xv * w0.y;
        acc[2] += xv * w0.z; acc[3] += xv * w0.w;
        acc[4] += xv * w1.x; acc[5] += xv * w1.y;
        acc[6] += xv * w1.z; acc[7] += xv * w1.w;
    }
    float* o = out + row * N_DIM + c0;
    #pragma unroll
    for (int j = 0; j < 8; ++j) o[j] = acc[j] + bias[c0 + j];
}

// ---------------------------------------------------------------------------
extern "C" void kernel_launch(void* const* d_in, const int* in_sizes, int n_in,
                              void* d_out, int out_size, void* d_ws, size_t ws_size,
                              hipStream_t stream) {
    const float* x    = (const float*)d_in[0];   // [4096, 256]
    const float* W    = (const float*)d_in[1];   // [256, 16384]
    const float* bias = (const float*)d_in[2];   // [16384]
    float* out        = (float*)d_out;           // [4096, 16384]

    const size_t wt_bytes = (size_t)N_DIM * K_DIM * 2;   // 8 MB
    const size_t xb_bytes = (size_t)M_DIM * K_DIM * 2;   // 2 MB

    if (ws_size >= wt_bytes + xb_bytes) {
        unsigned short* Wt = (unsigned short*)d_ws;
        unsigned short* xb = (unsigned short*)((char*)d_ws + wt_bytes);

        convert_kernel<<<256 + (M_DIM * K_DIM / 8) / 256, 256, 0, stream>>>(W, x, Wt, xb);
        gemm_kernel<<<(M_DIM / BM) * (N_DIM / BN), 256, 0, stream>>>(xb, Wt, bias, out);
    } else {
        const size_t total = (size_t)M_DIM * N_DIM / 8;
        fallback_kernel<<<(unsigned)(total / 256), 256, 0, stream>>>(x, W, bias, out);
    }
}